// Round 5
// baseline (179.330 us; speedup 1.0000x reference)
//
#include <hip/hip_runtime.h>

#define HH 128
#define WW 128
#define BB 4
#define CC 64
#define CHN 21
#define NPIX (HH*WW)     // 16384
#define NTAP 24
#define PAD 4
#define PW 136
#define PH 136
#define PPLANE (PW*PH)   // 18496
#define PWQ (PW/4)       // 34
#define CG 3             // channels per prop thread
#define NCG (CHN/CG)     // 7

__device__ __forceinline__ int clampi(int v, int lo, int hi) {
    return v < lo ? lo : (v > hi ? hi : v);
}

// ---- pad: edge-replicate feats AND mask into padded planes in one launch ---
__global__ __launch_bounds__(256) void pad_kernel(
    const float* __restrict__ feats, const float* __restrict__ mask,
    float* __restrict__ pfeats, float* __restrict__ pmask) {
    int t = blockIdx.x * blockDim.x + threadIdx.x;
    const int nfp = BB * CC;
    const int total = (nfp + BB * CHN) * PH * PWQ;
    if (t >= total) return;
    int q = t % PWQ;
    int rest = t / PWQ;
    int ph = rest % PH;
    int pl = rest / PH;
    const float* src;
    float* dst;
    if (pl < nfp) { src = feats + (size_t)pl * NPIX; dst = pfeats + (size_t)pl * PPLANE; }
    else { src = mask + (size_t)(pl - nfp) * NPIX; dst = pmask + (size_t)(pl - nfp) * PPLANE; }
    const float* sp = src + (size_t)clampi(ph - PAD, 0, HH - 1) * WW;
    float4 v;
    v.x = sp[clampi(q * 4 + 0 - PAD, 0, WW - 1)];
    v.y = sp[clampi(q * 4 + 1 - PAD, 0, WW - 1)];
    v.z = sp[clampi(q * 4 + 2 - PAD, 0, WW - 1)];
    v.w = sp[clampi(q * 4 + 3 - PAD, 0, WW - 1)];
    *((float4*)(dst + (size_t)ph * PW + q * 4)) = v;
}

// ---- fused affinity: thread = (2 px, 8 ch); shfl-reduce over 8-lane group --
// tid = pair*8 + cg.  Block covers 64 consecutive pixels (half a row).
// aff output layout: [b*NPIX + pix][24] contiguous per pixel.
__global__ __launch_bounds__(256) void affinity_kernel(
    const float* __restrict__ pfeats, float* __restrict__ aff) {
    int tid = threadIdx.x;
    int pair = tid >> 3;                       // 0..31
    int cg = tid & 7;                          // 0..7
    int gpx = blockIdx.x * 64 + pair * 2;      // even global pixel
    int b = gpx >> 14;
    int pix = gpx & (NPIX - 1);
    int h = pix >> 7;
    int w0 = pix & 127;

    float acc[48];
    #pragma unroll
    for (int k = 0; k < 48; ++k) acc[k] = 0.f;

    // base at padded (h+PAD, w0): padded col w0 == unpadded col w0-4
    const float* cp = pfeats + (size_t)(b * CC + cg * 8) * PPLANE
                    + (size_t)(h + PAD) * PW + w0;

    #pragma unroll
    for (int cc = 0; cc < 8; ++cc) {
        float tmp[48];
        float rb[10];
        float q0, q1, sum0, sum1, ss0, ss1;

#define ALOADROW(dy) { \
        const float2* rp = (const float2*)(cp + (dy) * PW); \
        float2 a0 = rp[0], a1 = rp[1], a2 = rp[2], a3 = rp[3], a4 = rp[4]; \
        rb[0]=a0.x; rb[1]=a0.y; rb[2]=a1.x; rb[3]=a1.y; rb[4]=a2.x; \
        rb[5]=a2.y; rb[6]=a3.x; rb[7]=a3.y; rb[8]=a4.x; rb[9]=a4.y; }

#define ATAP(k, di) { \
        float v0 = rb[(di)], v1 = rb[(di)+1]; \
        tmp[2*(k)]   = fabsf(v0 - q0); \
        tmp[2*(k)+1] = fabsf(v1 - q1); \
        sum0 += v0; ss0 = fmaf(v0, v0, ss0); \
        sum1 += v1; ss1 = fmaf(v1, v1, ss1); }

        ALOADROW(0);
        q0 = rb[4]; q1 = rb[5];
        sum0 = 3.f * q0; ss0 = 3.f * q0 * q0;
        sum1 = 3.f * q1; ss1 = 3.f * q1 * q1;
        ATAP(3,3)  ATAP(4,5)  ATAP(11,2) ATAP(12,6) ATAP(19,0) ATAP(20,8)
        ALOADROW(-1); ATAP(0,3)  ATAP(1,4)  ATAP(2,5)
        ALOADROW(1);  ATAP(5,3)  ATAP(6,4)  ATAP(7,5)
        ALOADROW(-2); ATAP(8,2)  ATAP(9,4)  ATAP(10,6)
        ALOADROW(2);  ATAP(13,2) ATAP(14,4) ATAP(15,6)
        ALOADROW(-4); ATAP(16,0) ATAP(17,4) ATAP(18,8)
        ALOADROW(4);  ATAP(21,0) ATAP(22,4) ATAP(23,8)

        float var0 = (ss0 - sum0 * sum0 * (1.f/27.f)) * (1.f/26.f);
        float var1 = (ss1 - sum1 * sum1 * (1.f/27.f)) * (1.f/26.f);
        float inv0 = 1.f / (1e-8f + 0.1f * sqrtf(fmaxf(var0, 0.f)));
        float inv1 = 1.f / (1e-8f + 0.1f * sqrtf(fmaxf(var1, 0.f)));
        #pragma unroll
        for (int k = 0; k < NTAP; ++k) {
            acc[2*k]   = fmaf(tmp[2*k],   -inv0, acc[2*k]);
            acc[2*k+1] = fmaf(tmp[2*k+1], -inv1, acc[2*k+1]);
        }
        cp += PPLANE;
    }

    // reduce the 8 channel-groups (8 consecutive lanes) -> lane cg==0
    #pragma unroll
    for (int k = 0; k < 48; ++k) {
        acc[k] += __shfl_down(acc[k], 1, 8);
        acc[k] += __shfl_down(acc[k], 2, 8);
        acc[k] += __shfl_down(acc[k], 4, 8);
    }

    if (cg == 0) {
        float m0 = -1e30f, m1 = -1e30f;
        #pragma unroll
        for (int k = 0; k < NTAP; ++k) {
            acc[2*k]   *= (1.f/CC);
            acc[2*k+1] *= (1.f/CC);
            m0 = fmaxf(m0, acc[2*k]);
            m1 = fmaxf(m1, acc[2*k+1]);
        }
        float s0 = 0.f, s1 = 0.f;
        #pragma unroll
        for (int k = 0; k < NTAP; ++k) {
            acc[2*k]   = __expf(acc[2*k]   - m0);
            acc[2*k+1] = __expf(acc[2*k+1] - m1);
            s0 += acc[2*k];
            s1 += acc[2*k+1];
        }
        float i0 = 1.f / s0, i1 = 1.f / s1;
        float* a0 = aff + (size_t)gpx * NTAP;
        #pragma unroll
        for (int k = 0; k < NTAP; k += 4)
            *((float4*)(a0 + k)) = make_float4(acc[2*k]*i0, acc[2*(k+1)]*i0,
                                               acc[2*(k+2)]*i0, acc[2*(k+3)]*i0);
        #pragma unroll
        for (int k = 0; k < NTAP; k += 4)
            *((float4*)(a0 + NTAP + k)) = make_float4(acc[2*k+1]*i1, acc[2*(k+1)+1]*i1,
                                                      acc[2*(k+2)+1]*i1, acc[2*(k+3)+1]*i1);
    }
}

// ---- prop: 1 px x 3 ch per thread; const-immediate tap offsets -------------
__global__ __launch_bounds__(256) void prop_kernel(
    const float* __restrict__ psrc_all, const float* __restrict__ aff,
    float* __restrict__ dst, int final_iter) {
    int idx = blockIdx.x * 256 + threadIdx.x;   // global px 0..65535
    int cg = blockIdx.y;                        // 0..6
    int w = idx & 127;
    int h = (idx >> 7) & 127;
    int b = idx >> 14;

    float A[NTAP];
    {
        const float4* ap = (const float4*)(aff + (size_t)idx * NTAP);
        float4 v0 = ap[0], v1 = ap[1], v2 = ap[2], v3 = ap[3], v4 = ap[4], v5 = ap[5];
        A[0]=v0.x; A[1]=v0.y; A[2]=v0.z; A[3]=v0.w;
        A[4]=v1.x; A[5]=v1.y; A[6]=v1.z; A[7]=v1.w;
        A[8]=v2.x; A[9]=v2.y; A[10]=v2.z; A[11]=v2.w;
        A[12]=v3.x; A[13]=v3.y; A[14]=v3.z; A[15]=v3.w;
        A[16]=v4.x; A[17]=v4.y; A[18]=v4.z; A[19]=v4.w;
        A[20]=v5.x; A[21]=v5.y; A[22]=v5.z; A[23]=v5.w;
    }

    #pragma unroll
    for (int cc = 0; cc < CG; ++cc) {
        int ch = cg * CG + cc;
        const float* base = psrc_all + (size_t)(b * CHN + ch) * PPLANE
                          + (size_t)(h + PAD) * PW + (w + PAD);
        float r = 0.f;
        r = fmaf(A[0],  base[-PW-1],   r);
        r = fmaf(A[1],  base[-PW],     r);
        r = fmaf(A[2],  base[-PW+1],   r);
        r = fmaf(A[3],  base[-1],      r);
        r = fmaf(A[4],  base[1],       r);
        r = fmaf(A[5],  base[PW-1],    r);
        r = fmaf(A[6],  base[PW],      r);
        r = fmaf(A[7],  base[PW+1],    r);
        r = fmaf(A[8],  base[-2*PW-2], r);
        r = fmaf(A[9],  base[-2*PW],   r);
        r = fmaf(A[10], base[-2*PW+2], r);
        r = fmaf(A[11], base[-2],      r);
        r = fmaf(A[12], base[2],       r);
        r = fmaf(A[13], base[2*PW-2],  r);
        r = fmaf(A[14], base[2*PW],    r);
        r = fmaf(A[15], base[2*PW+2],  r);
        r = fmaf(A[16], base[-4*PW-4], r);
        r = fmaf(A[17], base[-4*PW],   r);
        r = fmaf(A[18], base[-4*PW+4], r);
        r = fmaf(A[19], base[-4],      r);
        r = fmaf(A[20], base[4],       r);
        r = fmaf(A[21], base[4*PW-4],  r);
        r = fmaf(A[22], base[4*PW],    r);
        r = fmaf(A[23], base[4*PW+4],  r);

        if (final_iter) {
            dst[(size_t)(b * CHN + ch) * NPIX + h * WW + w] = r;
        } else {
            float* pd = dst + (size_t)(b * CHN + ch) * PPLANE;
            int pr = (h + PAD) * PW;
            pd[pr + PAD + w] = r;
            float4 e = make_float4(r, r, r, r);
            if (w == 0)      *((float4*)(pd + pr)) = e;
            if (w == WW-1)   *((float4*)(pd + pr + PAD + WW)) = e;
            if (h == 0) {
                #pragma unroll
                for (int rr = 0; rr < PAD; ++rr) {
                    pd[rr * PW + PAD + w] = r;
                    if (w == 0)    *((float4*)(pd + rr * PW)) = e;
                    if (w == WW-1) *((float4*)(pd + rr * PW + PAD + WW)) = e;
                }
            }
            if (h == HH-1) {
                #pragma unroll
                for (int rr = 0; rr < PAD; ++rr) {
                    int r2 = (PH - 1 - rr) * PW;
                    pd[r2 + PAD + w] = r;
                    if (w == 0)    *((float4*)(pd + r2)) = e;
                    if (w == WW-1) *((float4*)(pd + r2 + PAD + WW)) = e;
                }
            }
        }
    }
}

extern "C" void kernel_launch(void* const* d_in, const int* in_sizes, int n_in,
                              void* d_out, int out_size, void* d_ws, size_t ws_size,
                              hipStream_t stream) {
    const float* feats = (const float*)d_in[0];
    const float* mask  = (const float*)d_in[1];
    float* out = (float*)d_out;

    const size_t affE    = (size_t)BB * NPIX * NTAP;    // 1.57 M floats
    const size_t pbufE   = (size_t)BB * CHN * PPLANE;   // 1.55 M floats

    float* aff    = (float*)d_ws;
    float* pbuf0  = aff + affE;
    float* pbuf1  = pbuf0 + pbufE;
    float* pfeats = pbuf1 + pbufE;

    {
        int total = (BB * CC + BB * CHN) * PH * PWQ;
        pad_kernel<<<dim3((total + 255) / 256), dim3(256), 0, stream>>>(feats, mask, pfeats, pbuf0);
    }
    affinity_kernel<<<dim3(BB * NPIX / 64), dim3(256), 0, stream>>>(pfeats, aff);

    const float* src = pbuf0;
    for (int it = 1; it <= 10; ++it) {
        if (it < 10) {
            float* dst = (it & 1) ? pbuf1 : pbuf0;
            prop_kernel<<<dim3(256, NCG), dim3(256), 0, stream>>>(src, aff, dst, 0);
            src = dst;
        } else {
            prop_kernel<<<dim3(256, NCG), dim3(256), 0, stream>>>(src, aff, out, 1);
        }
    }
}

// Round 6
// 137.358 us; speedup vs baseline: 1.3056x; 1.3056x over previous
//
#include <hip/hip_runtime.h>

#define HH 128
#define WW 128
#define BB 4
#define CC 64
#define CHN 21
#define NPIX (HH*WW)     // 16384
#define NTAP 24
#define PAD 4
#define PW 136
#define PH 136
#define PPLANE (PW*PH)   // 18496
#define PWQ (PW/4)       // 34
#define CG 3             // channels per prop thread
#define NCG (CHN/CG)     // 7
#define AGR 4            // affinity channel groups per block
#define ACH (CC/AGR)     // 16 channels per thread

// Compile-time tap offsets in the padded plane (row stride PW).
// Order: dil 1 (8 taps), dil 2 (8), dil 4 (8) — same order in both kernels.
constexpr int TAPOFF[NTAP] = {
    -PW-1, -PW, -PW+1, -1, 1, PW-1, PW, PW+1,
    -2*PW-2, -2*PW, -2*PW+2, -2, 2, 2*PW-2, 2*PW, 2*PW+2,
    -4*PW-4, -4*PW, -4*PW+4, -4, 4, 4*PW-4, 4*PW, 4*PW+4
};

__device__ __forceinline__ int clampi(int v, int lo, int hi) {
    return v < lo ? lo : (v > hi ? hi : v);
}

// ---- pad: edge-replicate feats AND mask into padded planes in one launch ---
__global__ __launch_bounds__(256) void pad_kernel(
    const float* __restrict__ feats, const float* __restrict__ mask,
    float* __restrict__ pfeats, float* __restrict__ pmask) {
    int t = blockIdx.x * blockDim.x + threadIdx.x;
    const int nfp = BB * CC;
    const int total = (nfp + BB * CHN) * PH * PWQ;
    if (t >= total) return;
    int q = t % PWQ;
    int rest = t / PWQ;
    int ph = rest % PH;
    int pl = rest / PH;
    const float* src;
    float* dst;
    if (pl < nfp) { src = feats + (size_t)pl * NPIX; dst = pfeats + (size_t)pl * PPLANE; }
    else { src = mask + (size_t)(pl - nfp) * NPIX; dst = pmask + (size_t)(pl - nfp) * PPLANE; }
    const float* sp = src + (size_t)clampi(ph - PAD, 0, HH - 1) * WW;
    float4 v;
    v.x = sp[clampi(q * 4 + 0 - PAD, 0, WW - 1)];
    v.y = sp[clampi(q * 4 + 1 - PAD, 0, WW - 1)];
    v.z = sp[clampi(q * 4 + 2 - PAD, 0, WW - 1)];
    v.w = sp[clampi(q * 4 + 3 - PAD, 0, WW - 1)];
    *((float4*)(dst + (size_t)ph * PW + q * 4)) = v;
}

// ---- fused affinity: block = 64 px x 4 channel-groups; LDS reduce ----------
// aff output layout: [b][6][NPIX][4] (tap-quad SoA, coalesced for prop).
__global__ __launch_bounds__(256) void affinity_kernel(
    const float* __restrict__ pfeats, float* __restrict__ aff) {
    __shared__ float red[AGR][64][NTAP + 1];   // stride 25: conflict-free

    int t = threadIdx.x;
    int g = t >> 6;                  // 0..3 channel group
    int px = t & 63;                 // 0..63 pixel in half-row
    int blk = blockIdx.x;            // 0..1023
    int w = (blk & 1) * 64 + px;
    int h = (blk >> 1) & 127;
    int b = blk >> 8;

    const float* base0 = pfeats + (size_t)(b * CC + g * ACH) * PPLANE
                       + (size_t)(h + PAD) * PW + (w + PAD);

    float acc[NTAP];
    #pragma unroll
    for (int k = 0; k < NTAP; ++k) acc[k] = 0.f;

    for (int c = 0; c < ACH; ++c) {
        const float* base = base0 + (size_t)c * PPLANE;
        float q = base[0];
        float sum = 3.f * q, ss = 3.f * q * q;   // center window x3 dilations
        float v[NTAP];
        #pragma unroll
        for (int k = 0; k < NTAP; ++k) {
            float x = base[TAPOFF[k]];
            v[k] = x;
            sum += x;
            ss = fmaf(x, x, ss);
        }
        float var = (ss - sum * sum * (1.f/27.f)) * (1.f/26.f);
        float inv = 1.f / (1e-8f + 0.1f * sqrtf(fmaxf(var, 0.f)));
        #pragma unroll
        for (int k = 0; k < NTAP; ++k)
            acc[k] = fmaf(fabsf(v[k] - q), inv, acc[k]);   // positive sum; negate later
    }

    #pragma unroll
    for (int k = 0; k < NTAP; ++k) red[g][px][k] = acc[k];
    __syncthreads();

    if (t < 64) {
        float s[NTAP];
        #pragma unroll
        for (int k = 0; k < NTAP; ++k)
            s[k] = (red[0][t][k] + red[1][t][k]) + (red[2][t][k] + red[3][t][k]);
        // score_k = -s_k/64; softmax with max-sub == exp((min_s - s_k)/64)
        float mn = s[0];
        #pragma unroll
        for (int k = 1; k < NTAP; ++k) mn = fminf(mn, s[k]);
        float e[NTAP];
        float tot = 0.f;
        #pragma unroll
        for (int k = 0; k < NTAP; ++k) {
            e[k] = __expf((mn - s[k]) * (1.f/CC));
            tot += e[k];
        }
        float ivt = 1.f / tot;
        int pix = h * WW + (blk & 1) * 64 + t;
        #pragma unroll
        for (int j = 0; j < 6; ++j) {
            float4 o = make_float4(e[4*j]*ivt, e[4*j+1]*ivt, e[4*j+2]*ivt, e[4*j+3]*ivt);
            *((float4*)(aff + (((size_t)b * 6 + j) * NPIX + pix) * 4)) = o;
        }
    }
}

// ---- prop: 1 px x 3 ch per thread; coalesced SoA aff; imm tap offsets ------
__global__ __launch_bounds__(256) void prop_kernel(
    const float* __restrict__ psrc_all, const float* __restrict__ aff,
    float* __restrict__ dst, int final_iter) {
    int idx = blockIdx.x * 256 + threadIdx.x;   // global px 0..65535
    int cg = blockIdx.y;                        // 0..6
    int w = idx & 127;
    int h = (idx >> 7) & 127;
    int b = idx >> 14;
    int pix = idx & (NPIX - 1);

    float A[NTAP];
    #pragma unroll
    for (int j = 0; j < 6; ++j) {
        float4 v = *((const float4*)(aff + (((size_t)b * 6 + j) * NPIX + pix) * 4));
        A[4*j] = v.x; A[4*j+1] = v.y; A[4*j+2] = v.z; A[4*j+3] = v.w;
    }

    #pragma unroll
    for (int cc = 0; cc < CG; ++cc) {
        int ch = cg * CG + cc;
        const float* base = psrc_all + (size_t)(b * CHN + ch) * PPLANE
                          + (size_t)(h + PAD) * PW + (w + PAD);
        float r = 0.f;
        #pragma unroll
        for (int k = 0; k < NTAP; ++k) r = fmaf(A[k], base[TAPOFF[k]], r);

        if (final_iter) {
            dst[(size_t)(b * CHN + ch) * NPIX + h * WW + w] = r;
        } else {
            float* pd = dst + (size_t)(b * CHN + ch) * PPLANE;
            int pr = (h + PAD) * PW;
            pd[pr + PAD + w] = r;
            float4 e = make_float4(r, r, r, r);
            if (w == 0)      *((float4*)(pd + pr)) = e;
            if (w == WW-1)   *((float4*)(pd + pr + PAD + WW)) = e;
            if (h == 0) {
                #pragma unroll
                for (int rr = 0; rr < PAD; ++rr) {
                    pd[rr * PW + PAD + w] = r;
                    if (w == 0)    *((float4*)(pd + rr * PW)) = e;
                    if (w == WW-1) *((float4*)(pd + rr * PW + PAD + WW)) = e;
                }
            }
            if (h == HH-1) {
                #pragma unroll
                for (int rr = 0; rr < PAD; ++rr) {
                    int r2 = (PH - 1 - rr) * PW;
                    pd[r2 + PAD + w] = r;
                    if (w == 0)    *((float4*)(pd + r2)) = e;
                    if (w == WW-1) *((float4*)(pd + r2 + PAD + WW)) = e;
                }
            }
        }
    }
}

extern "C" void kernel_launch(void* const* d_in, const int* in_sizes, int n_in,
                              void* d_out, int out_size, void* d_ws, size_t ws_size,
                              hipStream_t stream) {
    const float* feats = (const float*)d_in[0];
    const float* mask  = (const float*)d_in[1];
    float* out = (float*)d_out;

    const size_t affE  = (size_t)BB * 6 * NPIX * 4;     // 1.57 M floats
    const size_t pbufE = (size_t)BB * CHN * PPLANE;     // 1.55 M floats

    float* aff    = (float*)d_ws;
    float* pbuf0  = aff + affE;
    float* pbuf1  = pbuf0 + pbufE;
    float* pfeats = pbuf1 + pbufE;

    {
        int total = (BB * CC + BB * CHN) * PH * PWQ;
        pad_kernel<<<dim3((total + 255) / 256), dim3(256), 0, stream>>>(feats, mask, pfeats, pbuf0);
    }
    affinity_kernel<<<dim3(BB * NPIX / 64), dim3(256), 0, stream>>>(pfeats, aff);

    const float* src = pbuf0;
    for (int it = 1; it <= 10; ++it) {
        if (it < 10) {
            float* dst = (it & 1) ? pbuf1 : pbuf0;
            prop_kernel<<<dim3(256, NCG), dim3(256), 0, stream>>>(src, aff, dst, 0);
            src = dst;
        } else {
            prop_kernel<<<dim3(256, NCG), dim3(256), 0, stream>>>(src, aff, out, 1);
        }
    }
}